// Round 19
// baseline (139.278 us; speedup 1.0000x reference)
//
#include <hip/hip_runtime.h>
#include <hip/hip_bf16.h>

typedef _Float16 f16x8 __attribute__((ext_vector_type(8)));
typedef float f32x4 __attribute__((ext_vector_type(4)));

#define TAU_Q 164           // ceil(5e-3 * 32768) = 10 sigma of 1-term fp16 dot noise (sigma~5e-4)
#define MASK_Q 2098790u     // (64.05)*32768: best-below -> rescue (masked-proto / all-negative guard)

// ---------------- kernel 1: per-proto norm + fp16-hi pack ----------------
// q[m] = counts>0 ? 1/||p_m|| : 0. B-hat = fp16(P*q), packed so MFMA B-fragment
// (p16=m>>4, kc) at lane L sits at byte (p16*8+kc)*1024 + L*16 (coalesced 1KB chunks).
// Masked protos: qm=0 -> all-zero fragments -> dot contributes exactly 0 (caught by MASK_Q).
__global__ __launch_bounds__(64) void prep_kernel(
    const float* __restrict__ P, const int* __restrict__ counts,
    float* __restrict__ q, int* __restrict__ wcount, f16x8* __restrict__ bhi) {
  const int m = blockIdx.x, lane = threadIdx.x;
  if (m == 0 && lane == 0) *wcount = 0;
  float4 v = *reinterpret_cast<const float4*>(P + (size_t)m * 256 + lane * 4);
  float s = v.x * v.x + v.y * v.y + v.z * v.z + v.w * v.w;
  for (int off = 32; off > 0; off >>= 1) s += __shfl_xor(s, off, 64);
  const float qm = (counts[m] > 0) ? (1.0f / sqrtf(s)) : 0.0f;
  if (lane == 0) q[m] = qm;
  if (lane < 32) {
    const int kg = lane;  // 8 k-elements per lane
    const float* src = P + (size_t)m * 256 + kg * 8;
    float4 v0 = *reinterpret_cast<const float4*>(src);
    float4 v1 = *reinterpret_cast<const float4*>(src + 4);
    float pe[8] = {v0.x, v0.y, v0.z, v0.w, v1.x, v1.y, v1.z, v1.w};
    f16x8 hi;
#pragma unroll
    for (int t = 0; t < 8; ++t) hi[t] = (_Float16)(pe[t] * qm);
    const int dst = ((m >> 4) * 8 + (kg >> 2)) * 64 + (kg & 3) * 16 + (m & 15);
    bhi[dst] = hi;
  }
}

// ---------------- kernel 2: fp16 MFMA screen -- B global->VGPR, A in LDS, zero main-loop sync
// 256 threads = 4 waves (2 rg of 64 rows x 2 cg of 128 protos). BM=128; wave tile 64x128 per
// pt (fc=8, 32 MFMA per kc). ldsA 64KB -> 2 blocks/CU = 2 waves/SIMD.
// WHY (r12..r18 post-mortem): every LDS-staged-B variant pinned at ~70us with LDS ~50% busy
// (~49K cyc/CU of b128 reads) and ~2000 cyc/step sync+issue overhead. This round: (1) wave
// tile 64x128 cuts A re-reads to 4x -> LDS ~12K cyc/CU; (2) B fragments load straight to
// REGISTERS (compiler-managed counted vmcnt, hoistable) -> no ldsB, no DMA, no barriers, no
// fences in the main loop at all. VGPR ~200-230 at 256 threads (r8 precedent: >128 granted).
__global__ __launch_bounds__(256) void screen_kernel(
    const float* __restrict__ E, const f16x8* __restrict__ bhi,
    int* __restrict__ out, int* __restrict__ wcount,
    int* __restrict__ wl, int wlcap) {
  __shared__ __align__(16) unsigned char ldsA[65536];  // 128 rows x 512B (hi fp16, K=256)

  const int tid = threadIdx.x;
  const int wave = tid >> 6, lane = tid & 63;
  const int rg = wave >> 1, cg = wave & 1;
  const int g = lane >> 4, c = lane & 15;
  const int blockRow = blockIdx.x * 128;
  const char* bhiB = (const char*)bhi + (size_t)lane * 16;

  // ---- stage A once: E[blockRow..+128][0..256) f32 -> hi fp16, swizzled ----
  {
    const int row = tid >> 1, half = tid & 1;  // 2 threads/row, 128 k each
    const float* src = E + (size_t)(blockRow + row) * 256 + half * 128;
    const int rswz = (row & 7) << 4;
#pragma unroll
    for (int o = 0; o < 16; ++o) {
      float4 v0 = *reinterpret_cast<const float4*>(src + o * 8);
      float4 v1 = *reinterpret_cast<const float4*>(src + o * 8 + 4);
      float e[8] = {v0.x, v0.y, v0.z, v0.w, v1.x, v1.y, v1.z, v1.w};
      f16x8 hi;
#pragma unroll
      for (int t = 0; t < 8; ++t) hi[t] = (_Float16)e[t];
      const int byte = (row * 512 + (half * 128 + o * 8) * 2) ^ rswz;
      *reinterpret_cast<f16x8*>(ldsA + byte) = hi;
    }
  }
  __syncthreads();  // the only barrier before the epilogue

  // quantized top-2 per lane: 16 row-slots (row = rg*64 + (s>>2)*16 + g*4 + (s&3))
  unsigned t1[16], t2[16];
#pragma unroll
  for (int s = 0; s < 16; ++s) { t1[s] = 0u; t2[s] = 0u; }

#pragma unroll 1
  for (int pt = 0; pt < 4; ++pt) {
    f32x4 acc[4][8];
#pragma unroll
    for (int fr = 0; fr < 4; ++fr)
#pragma unroll
      for (int fc = 0; fc < 8; ++fc) acc[fr][fc] = (f32x4){0.f, 0.f, 0.f, 0.f};

#pragma unroll
    for (int kc = 0; kc < 8; ++kc) {
      // ---- A fragments from LDS (4 x b128; swizzled, conflict-light) ----
      f16x8 ah[4];
#pragma unroll
      for (int fr = 0; fr < 4; ++fr) {
        const int rowA = rg * 64 + fr * 16 + c;
        const int ab = (rowA * 512 + kc * 64 + g * 16) ^ ((rowA & 7) << 4);
        ah[fr] = *reinterpret_cast<const f16x8*>(ldsA + ab);
      }
      // ---- B fragments global->VGPR in two fc-halves (register pressure), 32 MFMA ----
#pragma unroll
      for (int h = 0; h < 2; ++h) {
        f16x8 bf[4];
#pragma unroll
        for (int f = 0; f < 4; ++f) {
          const int p16 = pt * 16 + cg * 8 + h * 4 + f;
          bf[f] = *reinterpret_cast<const f16x8*>(bhiB + ((size_t)(p16 * 8 + kc) << 10));
        }
#pragma unroll
        for (int fr = 0; fr < 4; ++fr)
#pragma unroll
          for (int f = 0; f < 4; ++f)
            acc[fr][h * 4 + f] =
                __builtin_amdgcn_mfma_f32_16x16x32_f16(ah[fr], bf[f], acc[fr][h * 4 + f], 0, 0, 0);
      }
    }

    // ---- fold this pt's 128 proto-columns (per cg) into quantized top-2 ----
#pragma unroll
    for (int fc = 0; fc < 8; ++fc) {
      const unsigned mp = (unsigned)(1023 - (pt * 256 + cg * 128 + fc * 16 + c));
#pragma unroll
      for (int fr = 0; fr < 4; ++fr)
#pragma unroll
        for (int reg = 0; reg < 4; ++reg) {
          const int s = fr * 4 + reg;
          const float v = acc[fr][fc][reg];
          const unsigned k = ((unsigned)fmaf(v, 32768.0f, 2097152.0f) << 10) | mp;
          const unsigned lo = (k < t1[s]) ? k : t1[s];
          t1[s] = (k > t1[s]) ? k : t1[s];
          t2[s] = (lo > t2[s]) ? lo : t2[s];
        }
    }
  }

  // ---- cross-lane top-2 merge over the 16 c-lanes sharing each row ----
#pragma unroll
  for (int s = 0; s < 16; ++s) {
#pragma unroll
    for (int off = 1; off <= 8; off <<= 1) {
      const unsigned o1 = (unsigned)__shfl_xor((int)t1[s], off);
      const unsigned o2 = (unsigned)__shfl_xor((int)t2[s], off);
      const unsigned lo = (o1 < t1[s]) ? o1 : t1[s];
      t1[s] = (o1 > t1[s]) ? o1 : t1[s];
      const unsigned hi2 = (o2 > t2[s]) ? o2 : t2[s];
      t2[s] = (lo > hi2) ? lo : hi2;
    }
  }

  __syncthreads();  // all waves done with ldsA -> reuse for cross-cg merge
  unsigned* mg = reinterpret_cast<unsigned*>(ldsA);  // [128 rows][2 cg][2]
  if (c == 0) {
#pragma unroll
    for (int s = 0; s < 16; ++s) {
      const int row = rg * 64 + (s >> 2) * 16 + g * 4 + (s & 3);
      mg[(row * 2 + cg) * 2 + 0] = t1[s];
      mg[(row * 2 + cg) * 2 + 1] = t2[s];
    }
  }
  __syncthreads();
  if (tid < 128) {
    const unsigned a1v = mg[(tid * 2 + 0) * 2 + 0], a2v = mg[(tid * 2 + 0) * 2 + 1];
    const unsigned b1v = mg[(tid * 2 + 1) * 2 + 0], b2v = mg[(tid * 2 + 1) * 2 + 1];
    const unsigned lo = (a1v < b1v) ? a1v : b1v;
    const unsigned T1 = (a1v > b1v) ? a1v : b1v;
    unsigned T2 = (a2v > b2v) ? a2v : b2v;
    T2 = (lo > T2) ? lo : T2;
    const int grow = blockRow + tid;
    out[grow] = 1023 - (int)(T1 & 1023u);
    const unsigned iq1 = T1 >> 10, iq2 = T2 >> 10;
    if ((int)(iq1 - iq2) < TAU_Q || iq1 < MASK_Q) {
      const int p = atomicAdd(wcount, 1);
      if (p < wlcap) wl[p] = grow;
    }
  }
}

// ---------------- kernel 3: exact f32 rescue over the worklist (16 rows/batch) ----------------
// Round-1-identical accumulation per (row, proto): ONE ascending-k fmaf chain over k=0..255
// (x,y,z,w within each float4), then v = acc*q, ties to the smaller proto index.
__global__ __launch_bounds__(256) void rescue_kernel(
    const float* __restrict__ E, const float* __restrict__ P,
    const float* __restrict__ q, int* __restrict__ out,
    const int* __restrict__ wcount, const int* __restrict__ wl, int wlcap) {
  __shared__ float Elds[16][260];
  __shared__ int rowsS[16];
  __shared__ float wv[16][4];
  __shared__ int wm[16][4];

  const int tid = threadIdx.x;
  const int wave = tid >> 6, lane = tid & 63;
  int total = *wcount;
  if (total > wlcap) total = wlcap;

  for (int b0 = blockIdx.x * 16; b0 < total; b0 += gridDim.x * 16) {
    const int nb = min(16, total - b0);
    __syncthreads();
    if (tid < 16) rowsS[tid] = wl[b0 + (tid < nb ? tid : 0)];
    __syncthreads();
#pragma unroll
    for (int u = 0; u < 4; ++u) {
      const int unit = u * 256 + tid, r = unit >> 6, k4 = unit & 63;
      *reinterpret_cast<float4*>(&Elds[r][k4 * 4]) =
          *reinterpret_cast<const float4*>(E + (size_t)rowsS[r] * 256 + k4 * 4);
    }
    __syncthreads();

    float acc[16][4];  // 16 rows x 4 protos (m = tid + 256*j)
#pragma unroll
    for (int r = 0; r < 16; ++r)
#pragma unroll
      for (int j = 0; j < 4; ++j) acc[r][j] = 0.f;

    for (int k16 = 0; k16 < 16; ++k16) {  // 16 consecutive k per step
#pragma unroll
      for (int jp = 0; jp < 2; ++jp) {    // protos in pairs (register budget)
        float4 pv[2][4];
#pragma unroll
        for (int jj = 0; jj < 2; ++jj) {
          const float* ps = P + (size_t)(tid + 256 * (jp * 2 + jj)) * 256 + k16 * 16;
#pragma unroll
          for (int u = 0; u < 4; ++u)
            pv[jj][u] = *reinterpret_cast<const float4*>(ps + u * 4);
        }
#pragma unroll
        for (int r = 0; r < 16; ++r) {
#pragma unroll
          for (int jj = 0; jj < 2; ++jj) {
            const int j = jp * 2 + jj;
            float a = acc[r][j];
#pragma unroll
            for (int u = 0; u < 4; ++u) {
              const float4 ev = *reinterpret_cast<const float4*>(&Elds[r][k16 * 16 + u * 4]);
              a = fmaf(pv[jj][u].x, ev.x, a);
              a = fmaf(pv[jj][u].y, ev.y, a);
              a = fmaf(pv[jj][u].z, ev.z, a);
              a = fmaf(pv[jj][u].w, ev.w, a);
            }
            acc[r][j] = a;
          }
        }
      }
    }

    float qv[4];
#pragma unroll
    for (int j = 0; j < 4; ++j) qv[j] = q[tid + 256 * j];

#pragma unroll
    for (int r = 0; r < 16; ++r) {
      float bv = -3.0e38f;
      int bm = 0;
#pragma unroll
      for (int j = 0; j < 4; ++j) {  // m ascending -> strict > keeps lowest m
        const float v = (qv[j] > 0.f) ? acc[r][j] * qv[j] : -1.0e30f;
        if (v > bv) { bv = v; bm = tid + 256 * j; }
      }
#pragma unroll
      for (int off = 1; off <= 32; off <<= 1) {
        const float ov = __shfl_xor(bv, off);
        const int om = __shfl_xor(bm, off);
        if (ov > bv || (ov == bv && om < bm)) { bv = ov; bm = om; }
      }
      if (lane == 0) { wv[r][wave] = bv; wm[r][wave] = bm; }
    }
    __syncthreads();
    if (tid < 16) {
      float bv = wv[tid][0];
      int bm = wm[tid][0];
#pragma unroll
      for (int w = 1; w < 4; ++w) {
        const float ov = wv[tid][w];
        const int om = wm[tid][w];
        if (ov > bv || (ov == bv && om < bm)) { bv = ov; bm = om; }
      }
      if (tid < nb) out[rowsS[tid]] = bm;
    }
    __syncthreads();
  }
}

extern "C" void kernel_launch(void* const* d_in, const int* in_sizes, int n_in,
                              void* d_out, int out_size, void* d_ws, size_t ws_size,
                              hipStream_t stream) {
  const float* E = (const float*)d_in[0];
  const float* P = (const float*)d_in[1];
  const int* counts = (const int*)d_in[2];
  const int M = in_sizes[2];            // 1024
  const int Dd = in_sizes[1] / M;       // 256
  const int N = in_sizes[0] / Dd;       // 65536
  int* out = (int*)d_out;

  // workspace: q (4KB) | wcount @4096 | bhi @8192 (512KB) | worklist @532480
  float* qv = (float*)d_ws;
  int* wcount = (int*)((char*)d_ws + 4096);
  f16x8* bhi = (f16x8*)((char*)d_ws + 8192);
  int* wl = (int*)((char*)d_ws + 8192 + 524288);
  long long cap = ((long long)ws_size - (8192 + 524288)) / 4;
  if (cap < 0) cap = 0;
  if (cap > N) cap = N;
  int wlcap = (int)cap;

  prep_kernel<<<M, 64, 0, stream>>>(P, counts, qv, wcount, bhi);
  screen_kernel<<<N / 128, 256, 0, stream>>>(E, bhi, out, wcount, wl, wlcap);
  rescue_kernel<<<256, 256, 0, stream>>>(E, P, qv, out, wcount, wl, wlcap);
}

// Round 20
// 133.695 us; speedup vs baseline: 1.0418x; 1.0418x over previous
//
#include <hip/hip_runtime.h>
#include <hip/hip_bf16.h>

typedef _Float16 f16x8 __attribute__((ext_vector_type(8)));
typedef float f32x4 __attribute__((ext_vector_type(4)));

#define TAU_Q 164           // ceil(5e-3 * 32768) = 10 sigma of 1-term fp16 dot noise (sigma~5e-4)
#define MASK_Q 2098790u     // (64.05)*32768: best-below -> rescue (masked-proto / all-negative guard)

typedef const __attribute__((address_space(1))) void gas_void;
typedef __attribute__((address_space(3))) void las_void;

__device__ __forceinline__ void gload_lds16(const void* g, void* l) {
  // async global->LDS DMA, 16B/lane; LDS dest = wave-uniform base + lane*16
  __builtin_amdgcn_global_load_lds((gas_void*)g, (las_void*)l, 16, 0, 0);
}

// ---------------- kernel 1: per-proto norm + fp16-hi pack ----------------
// q[m] = counts>0 ? 1/||p_m|| : 0. B-hat = fp16(P*q), packed so MFMA B-fragment
// (p16=m>>4, kc) at lane L sits at byte (p16*8+kc)*1024 + L*16 (coalesced 1KB chunks).
// Chunk property: protos [c*128,(c+1)*128) = bytes [c*64KB,(c+1)*64KB) -- contiguous.
__global__ __launch_bounds__(64) void prep_kernel(
    const float* __restrict__ P, const int* __restrict__ counts,
    float* __restrict__ q, int* __restrict__ wcount, f16x8* __restrict__ bhi) {
  const int m = blockIdx.x, lane = threadIdx.x;
  if (m == 0 && lane == 0) *wcount = 0;
  float4 v = *reinterpret_cast<const float4*>(P + (size_t)m * 256 + lane * 4);
  float s = v.x * v.x + v.y * v.y + v.z * v.z + v.w * v.w;
  for (int off = 32; off > 0; off >>= 1) s += __shfl_xor(s, off, 64);
  const float qm = (counts[m] > 0) ? (1.0f / sqrtf(s)) : 0.0f;
  if (lane == 0) q[m] = qm;
  if (lane < 32) {
    const int kg = lane;  // 8 k-elements per lane
    const float* src = P + (size_t)m * 256 + kg * 8;
    float4 v0 = *reinterpret_cast<const float4*>(src);
    float4 v1 = *reinterpret_cast<const float4*>(src + 4);
    float pe[8] = {v0.x, v0.y, v0.z, v0.w, v1.x, v1.y, v1.z, v1.w};
    f16x8 hi;
#pragma unroll
    for (int t = 0; t < 8; ++t) hi[t] = (_Float16)(pe[t] * qm);
    const int dst = ((m >> 4) * 8 + (kg >> 2)) * 64 + (kg & 3) * 16 + (m & 15);
    bhi[dst] = hi;
  }
}

// ---------------- kernel 2: fp16 MFMA screen -- coarse 64KB B-chunks, fr4 x fc4 tiles ------
// 256 threads = 4 waves (2 rg of 64 rows x 2 cg of 64 protos). BM=128.
// A: 64KB LDS (hi fp16, K=256, swizzled). B: SINGLE 64KB buffer = 128 protos staged per
// chunk in ONE burst (16 DMA issues/thread; latency paid once per chunk, not per 8KB).
// 8 chunks x {barrier, stage, barrier, 128 MFMA/wave + fold}. Sync cost amortized 4x vs
// r12/r18 (2 barriers per 2480-cyc compute). Wave tile 64x64 (fr=4,fc=4): LDS-read ratio
// 0.5 b128/MFMA -- the minimum that fits 160KB with B in LDS (r19's global-B had 0.375 but
// paid ~900cyc L2/L3 latency per fragment batch; r12-r18's 0.75-1.0 ratios + per-8KB sync
// pinned all seven prior variants at 68-85us).
__global__ __launch_bounds__(256) void screen_kernel(
    const float* __restrict__ E, const f16x8* __restrict__ bhi,
    int* __restrict__ out, int* __restrict__ wcount,
    int* __restrict__ wl, int wlcap) {
  __shared__ __align__(16) unsigned char ldsA[65536];  // 128 rows x 512B (hi fp16, K=256)
  __shared__ __align__(16) unsigned char ldsB[65536];  // 1 buf = 128 protos x 512B

  const int tid = threadIdx.x;
  const int wave = tid >> 6, lane = tid & 63;
  const int rg = wave >> 1, cg = wave & 1;
  const int g = lane >> 4, c = lane & 15;
  const int blockRow = blockIdx.x * 128;
  const char* bhiB = (const char*)bhi;

  // ---- B stage: chunk ch = contiguous 64KB of bhi -> linear LDS (wave w: 16KB slice) ----
  auto stageB = [&](int ch) {
#pragma unroll
    for (int i = 0; i < 16; ++i) {
      const int j = wave * 16 + i;  // fragment index within chunk
      gload_lds16(bhiB + ((size_t)ch << 16) + ((size_t)j << 10) + (size_t)lane * 16,
                  (char*)ldsB + (j << 10));
    }
  };

  stageB(0);  // latency hides under the A-stage below

  // ---- stage A once: E[blockRow..+128][0..256) f32 -> hi fp16, swizzled ----
  {
    const int row = tid >> 1, half = tid & 1;  // 2 threads/row, 128 k each
    const float* src = E + (size_t)(blockRow + row) * 256 + half * 128;
    const int rswz = (row & 7) << 4;
#pragma unroll
    for (int o = 0; o < 16; ++o) {
      float4 v0 = *reinterpret_cast<const float4*>(src + o * 8);
      float4 v1 = *reinterpret_cast<const float4*>(src + o * 8 + 4);
      float e[8] = {v0.x, v0.y, v0.z, v0.w, v1.x, v1.y, v1.z, v1.w};
      f16x8 hi;
#pragma unroll
      for (int t = 0; t < 8; ++t) hi[t] = (_Float16)e[t];
      const int byte = (row * 512 + (half * 128 + o * 8) * 2) ^ rswz;
      *reinterpret_cast<f16x8*>(ldsA + byte) = hi;
    }
  }
  __syncthreads();  // A staged; barrier drains vmcnt -> chunk 0 valid

  // quantized top-2 per lane: 16 row-slots (row = rg*64 + (s>>2)*16 + g*4 + (s&3))
  unsigned t1[16], t2[16];
#pragma unroll
  for (int s = 0; s < 16; ++s) { t1[s] = 0u; t2[s] = 0u; }

#pragma unroll 1
  for (int ch = 0; ch < 8; ++ch) {
    f32x4 acc[4][4];
#pragma unroll
    for (int fr = 0; fr < 4; ++fr)
#pragma unroll
      for (int fc = 0; fc < 4; ++fc) acc[fr][fc] = (f32x4){0.f, 0.f, 0.f, 0.f};

#pragma unroll
    for (int kc = 0; kc < 8; ++kc) {
      // ---- A fragments (4 x b128, swizzled) ----
      f16x8 ah[4];
#pragma unroll
      for (int fr = 0; fr < 4; ++fr) {
        const int rowA = rg * 64 + fr * 16 + c;
        const int ab = (rowA * 512 + kc * 64 + g * 16) ^ ((rowA & 7) << 4);
        ah[fr] = *reinterpret_cast<const f16x8*>(ldsA + ab);
      }
      // ---- B fragments (4 x b128, contiguous 1KB chunks: conflict-free) ----
      f16x8 bf[4];
#pragma unroll
      for (int fc = 0; fc < 4; ++fc) {
        const int j = (cg * 4 + fc) * 8 + kc;
        bf[fc] = *reinterpret_cast<const f16x8*>((const char*)ldsB + (j << 10) + (size_t)lane * 16);
      }
      // ---- 16 MFMA ----
#pragma unroll
      for (int fr = 0; fr < 4; ++fr)
#pragma unroll
        for (int fc = 0; fc < 4; ++fc)
          acc[fr][fc] = __builtin_amdgcn_mfma_f32_16x16x32_f16(ah[fr], bf[fc], acc[fr][fc], 0, 0, 0);
    }

    // ---- fold this chunk's 64 proto-columns (per cg) into quantized top-2 ----
#pragma unroll
    for (int fc = 0; fc < 4; ++fc) {
      const unsigned mp = (unsigned)(1023 - (ch * 128 + cg * 64 + fc * 16 + c));
#pragma unroll
      for (int fr = 0; fr < 4; ++fr)
#pragma unroll
        for (int reg = 0; reg < 4; ++reg) {
          const int s = fr * 4 + reg;
          const float v = acc[fr][fc][reg];
          const unsigned k = ((unsigned)fmaf(v, 32768.0f, 2097152.0f) << 10) | mp;
          const unsigned lo = (k < t1[s]) ? k : t1[s];
          t1[s] = (k > t1[s]) ? k : t1[s];
          t2[s] = (lo > t2[s]) ? lo : t2[s];
        }
    }

    // ---- next chunk: all waves done reading ldsB -> stage, then fence ----
    if (ch < 7) {
      __syncthreads();          // readers of chunk ch done
      stageB(ch + 1);           // one 64KB burst
      __syncthreads();          // drains the DMA (vmcnt) -> chunk ch+1 valid
    }
  }

  // ---- cross-lane top-2 merge over the 16 c-lanes sharing each row ----
#pragma unroll
  for (int s = 0; s < 16; ++s) {
#pragma unroll
    for (int off = 1; off <= 8; off <<= 1) {
      const unsigned o1 = (unsigned)__shfl_xor((int)t1[s], off);
      const unsigned o2 = (unsigned)__shfl_xor((int)t2[s], off);
      const unsigned lo = (o1 < t1[s]) ? o1 : t1[s];
      t1[s] = (o1 > t1[s]) ? o1 : t1[s];
      const unsigned hi2 = (o2 > t2[s]) ? o2 : t2[s];
      t2[s] = (lo > hi2) ? lo : hi2;
    }
  }

  __syncthreads();  // all waves done with ldsA/ldsB -> reuse ldsA for cross-cg merge
  unsigned* mg = reinterpret_cast<unsigned*>(ldsA);  // [128 rows][2 cg][2]
  if (c == 0) {
#pragma unroll
    for (int s = 0; s < 16; ++s) {
      const int row = rg * 64 + (s >> 2) * 16 + g * 4 + (s & 3);
      mg[(row * 2 + cg) * 2 + 0] = t1[s];
      mg[(row * 2 + cg) * 2 + 1] = t2[s];
    }
  }
  __syncthreads();
  if (tid < 128) {
    const unsigned a1v = mg[(tid * 2 + 0) * 2 + 0], a2v = mg[(tid * 2 + 0) * 2 + 1];
    const unsigned b1v = mg[(tid * 2 + 1) * 2 + 0], b2v = mg[(tid * 2 + 1) * 2 + 1];
    const unsigned lo = (a1v < b1v) ? a1v : b1v;
    const unsigned T1 = (a1v > b1v) ? a1v : b1v;
    unsigned T2 = (a2v > b2v) ? a2v : b2v;
    T2 = (lo > T2) ? lo : T2;
    const int grow = blockRow + tid;
    out[grow] = 1023 - (int)(T1 & 1023u);
    const unsigned iq1 = T1 >> 10, iq2 = T2 >> 10;
    if ((int)(iq1 - iq2) < TAU_Q || iq1 < MASK_Q) {
      const int p = atomicAdd(wcount, 1);
      if (p < wlcap) wl[p] = grow;
    }
  }
}

// ---------------- kernel 3: exact f32 rescue over the worklist (16 rows/batch) ----------------
// Round-1-identical accumulation per (row, proto): ONE ascending-k fmaf chain over k=0..255
// (x,y,z,w within each float4), then v = acc*q, ties to the smaller proto index.
__global__ __launch_bounds__(256) void rescue_kernel(
    const float* __restrict__ E, const float* __restrict__ P,
    const float* __restrict__ q, int* __restrict__ out,
    const int* __restrict__ wcount, const int* __restrict__ wl, int wlcap) {
  __shared__ float Elds[16][260];
  __shared__ int rowsS[16];
  __shared__ float wv[16][4];
  __shared__ int wm[16][4];

  const int tid = threadIdx.x;
  const int wave = tid >> 6, lane = tid & 63;
  int total = *wcount;
  if (total > wlcap) total = wlcap;

  for (int b0 = blockIdx.x * 16; b0 < total; b0 += gridDim.x * 16) {
    const int nb = min(16, total - b0);
    __syncthreads();
    if (tid < 16) rowsS[tid] = wl[b0 + (tid < nb ? tid : 0)];
    __syncthreads();
#pragma unroll
    for (int u = 0; u < 4; ++u) {
      const int unit = u * 256 + tid, r = unit >> 6, k4 = unit & 63;
      *reinterpret_cast<float4*>(&Elds[r][k4 * 4]) =
          *reinterpret_cast<const float4*>(E + (size_t)rowsS[r] * 256 + k4 * 4);
    }
    __syncthreads();

    float acc[16][4];  // 16 rows x 4 protos (m = tid + 256*j)
#pragma unroll
    for (int r = 0; r < 16; ++r)
#pragma unroll
      for (int j = 0; j < 4; ++j) acc[r][j] = 0.f;

    for (int k16 = 0; k16 < 16; ++k16) {  // 16 consecutive k per step
#pragma unroll
      for (int jp = 0; jp < 2; ++jp) {    // protos in pairs (register budget)
        float4 pv[2][4];
#pragma unroll
        for (int jj = 0; jj < 2; ++jj) {
          const float* ps = P + (size_t)(tid + 256 * (jp * 2 + jj)) * 256 + k16 * 16;
#pragma unroll
          for (int u = 0; u < 4; ++u)
            pv[jj][u] = *reinterpret_cast<const float4*>(ps + u * 4);
        }
#pragma unroll
        for (int r = 0; r < 16; ++r) {
#pragma unroll
          for (int jj = 0; jj < 2; ++jj) {
            const int j = jp * 2 + jj;
            float a = acc[r][j];
#pragma unroll
            for (int u = 0; u < 4; ++u) {
              const float4 ev = *reinterpret_cast<const float4*>(&Elds[r][k16 * 16 + u * 4]);
              a = fmaf(pv[jj][u].x, ev.x, a);
              a = fmaf(pv[jj][u].y, ev.y, a);
              a = fmaf(pv[jj][u].z, ev.z, a);
              a = fmaf(pv[jj][u].w, ev.w, a);
            }
            acc[r][j] = a;
          }
        }
      }
    }

    float qv[4];
#pragma unroll
    for (int j = 0; j < 4; ++j) qv[j] = q[tid + 256 * j];

#pragma unroll
    for (int r = 0; r < 16; ++r) {
      float bv = -3.0e38f;
      int bm = 0;
#pragma unroll
      for (int j = 0; j < 4; ++j) {  // m ascending -> strict > keeps lowest m
        const float v = (qv[j] > 0.f) ? acc[r][j] * qv[j] : -1.0e30f;
        if (v > bv) { bv = v; bm = tid + 256 * j; }
      }
#pragma unroll
      for (int off = 1; off <= 32; off <<= 1) {
        const float ov = __shfl_xor(bv, off);
        const int om = __shfl_xor(bm, off);
        if (ov > bv || (ov == bv && om < bm)) { bv = ov; bm = om; }
      }
      if (lane == 0) { wv[r][wave] = bv; wm[r][wave] = bm; }
    }
    __syncthreads();
    if (tid < 16) {
      float bv = wv[tid][0];
      int bm = wm[tid][0];
#pragma unroll
      for (int w = 1; w < 4; ++w) {
        const float ov = wv[tid][w];
        const int om = wm[tid][w];
        if (ov > bv || (ov == bv && om < bm)) { bv = ov; bm = om; }
      }
      if (tid < nb) out[rowsS[tid]] = bm;
    }
    __syncthreads();
  }
}

extern "C" void kernel_launch(void* const* d_in, const int* in_sizes, int n_in,
                              void* d_out, int out_size, void* d_ws, size_t ws_size,
                              hipStream_t stream) {
  const float* E = (const float*)d_in[0];
  const float* P = (const float*)d_in[1];
  const int* counts = (const int*)d_in[2];
  const int M = in_sizes[2];            // 1024
  const int Dd = in_sizes[1] / M;       // 256
  const int N = in_sizes[0] / Dd;       // 65536
  int* out = (int*)d_out;

  // workspace: q (4KB) | wcount @4096 | bhi @8192 (512KB) | worklist @532480
  float* qv = (float*)d_ws;
  int* wcount = (int*)((char*)d_ws + 4096);
  f16x8* bhi = (f16x8*)((char*)d_ws + 8192);
  int* wl = (int*)((char*)d_ws + 8192 + 524288);
  long long cap = ((long long)ws_size - (8192 + 524288)) / 4;
  if (cap < 0) cap = 0;
  if (cap > N) cap = N;
  int wlcap = (int)cap;

  prep_kernel<<<M, 64, 0, stream>>>(P, counts, qv, wcount, bhi);
  screen_kernel<<<N / 128, 256, 0, stream>>>(E, bhi, out, wcount, wl, wlcap);
  rescue_kernel<<<256, 256, 0, stream>>>(E, P, qv, out, wcount, wl, wlcap);
}

// Round 21
// 111.669 us; speedup vs baseline: 1.2472x; 1.1972x over previous
//
#include <hip/hip_runtime.h>
#include <hip/hip_bf16.h>

typedef _Float16 f16x8 __attribute__((ext_vector_type(8)));
typedef float f32x4 __attribute__((ext_vector_type(4)));

#define TAU_Q 164           // ceil(5e-3 * 32768) = 10 sigma of 1-term fp16 dot noise (sigma~5e-4)
#define MASK_Q 2098790u     // (64.05)*32768: best-below -> rescue (masked-proto / all-negative guard)

typedef const __attribute__((address_space(1))) void gas_void;
typedef __attribute__((address_space(3))) void las_void;

__device__ __forceinline__ void gload_lds16(const void* g, void* l) {
  // async global->LDS DMA, 16B/lane; LDS dest = wave-uniform base + lane*16
  __builtin_amdgcn_global_load_lds((gas_void*)g, (las_void*)l, 16, 0, 0);
}

// ---------------- kernel 1: per-proto norm + fp16-hi pack ----------------
// q[m] = counts>0 ? 1/||p_m|| : 0. B-hat = fp16(P*q), packed so MFMA B-fragment
// (p16=m>>4, kc) at lane L sits at byte (p16*8+kc)*1024 + L*16 (coalesced 1KB chunks).
// Chunk property: protos [c*64,(c+1)*64) = bytes [c*32KB,(c+1)*32KB) -- contiguous.
__global__ __launch_bounds__(64) void prep_kernel(
    const float* __restrict__ P, const int* __restrict__ counts,
    float* __restrict__ q, int* __restrict__ wcount, f16x8* __restrict__ bhi) {
  const int m = blockIdx.x, lane = threadIdx.x;
  if (m == 0 && lane == 0) *wcount = 0;
  float4 v = *reinterpret_cast<const float4*>(P + (size_t)m * 256 + lane * 4);
  float s = v.x * v.x + v.y * v.y + v.z * v.z + v.w * v.w;
  for (int off = 32; off > 0; off >>= 1) s += __shfl_xor(s, off, 64);
  const float qm = (counts[m] > 0) ? (1.0f / sqrtf(s)) : 0.0f;
  if (lane == 0) q[m] = qm;
  if (lane < 32) {
    const int kg = lane;  // 8 k-elements per lane
    const float* src = P + (size_t)m * 256 + kg * 8;
    float4 v0 = *reinterpret_cast<const float4*>(src);
    float4 v1 = *reinterpret_cast<const float4*>(src + 4);
    float pe[8] = {v0.x, v0.y, v0.z, v0.w, v1.x, v1.y, v1.z, v1.w};
    f16x8 hi;
#pragma unroll
    for (int t = 0; t < 8; ++t) hi[t] = (_Float16)(pe[t] * qm);
    const int dst = ((m >> 4) * 8 + (kg >> 2)) * 64 + (kg & 3) * 16 + (m & 15);
    bhi[dst] = hi;
  }
}

// ---------------- kernel 2: fp16 MFMA screen -- A-in-reg + coarse dbuf B + 2 resident blocks
// 256 threads = 4 waves (2 rg x 2 cg). BM=128. A: ENTIRELY in VGPRs (a[4][8] f16x8 = 128
// regs = wave's 64 rows x K=256; r15-proven). B: shared LDS, 16 chunks of 64 protos x full
// K=256 (32KB, contiguous in bhi), double-buffered 2x32KB, ONE barrier per chunk (ordering:
// stage into buf^1 -> compute buf -> barrier; barrier both frees buf^1's old readers and
// drains this iter's DMA). LDS=64KB + VGPR~215 -> TWO resident blocks/CU: when one block
// sits at its barrier/DMA-drain the other's waves keep matrix+VALU+LDS pipes fed (the
// r12..r20 failure mode was single-resident lockstep or per-wave depth-1 fences).
// LDS-read ratio: 2 b128 per 8 MFMA = 0.25 (lowest yet; A never touches LDS).
__global__ __launch_bounds__(256) void screen_kernel(
    const float* __restrict__ E, const f16x8* __restrict__ bhi,
    int* __restrict__ out, int* __restrict__ wcount,
    int* __restrict__ wl, int wlcap) {
  __shared__ __align__(16) unsigned char ldsB[65536];  // 2 bufs x 32KB (32 chunks of 1KB)

  const int tid = threadIdx.x;
  const int wave = tid >> 6, lane = tid & 63;
  const int rg = wave >> 1, cg = wave & 1;
  const int g = lane >> 4, c = lane & 15;
  const int blockRow = blockIdx.x * 128;
  const char* bhiB = (const char*)bhi;

  // ---- B stage: chunk ch (64 protos, full K) = contiguous 32KB; wave stages 8 fragments ----
  auto stageB = [&](int b, int ch) {
#pragma unroll
    for (int i = 0; i < 8; ++i) {
      const int j = wave * 8 + i;  // fragment 0..31 within chunk
      gload_lds16(bhiB + ((size_t)ch << 15) + ((size_t)j << 10) + (size_t)lane * 16,
                  (char*)ldsB + (b << 15) + (j << 10));
    }
  };

  stageB(0, 0);  // latency hides under the A load+convert below

  // ---- load A into registers: wave's 64 rows x K=256, f32 -> hi fp16, fragment layout ----
  // a[fr][kc] elem t = E[blockRow + rg*64 + fr*16 + c][kc*32 + g*8 + t]
  f16x8 a[4][8];
#pragma unroll
  for (int fr = 0; fr < 4; ++fr) {
    const float* rowp = E + (size_t)(blockRow + rg * 64 + fr * 16 + c) * 256 + g * 8;
#pragma unroll
    for (int kc = 0; kc < 8; ++kc) {
      const float* p = rowp + kc * 32;
      float4 v0 = *reinterpret_cast<const float4*>(p);
      float4 v1 = *reinterpret_cast<const float4*>(p + 4);
      f16x8 h;
      h[0] = (_Float16)v0.x; h[1] = (_Float16)v0.y;
      h[2] = (_Float16)v0.z; h[3] = (_Float16)v0.w;
      h[4] = (_Float16)v1.x; h[5] = (_Float16)v1.y;
      h[6] = (_Float16)v1.z; h[7] = (_Float16)v1.w;
      a[fr][kc] = h;
    }
  }
  __syncthreads();  // drains chunk-0 DMA (and syncs the block)

  // quantized top-2 per lane: 16 row-slots (row = rg*64 + (s>>2)*16 + g*4 + (s&3))
  unsigned t1[16], t2[16];
#pragma unroll
  for (int s = 0; s < 16; ++s) { t1[s] = 0u; t2[s] = 0u; }

#pragma unroll 1
  for (int ch = 0; ch < 16; ++ch) {
    const int buf = ch & 1;
    if (ch < 15) stageB(buf ^ 1, ch + 1);  // buf^1's readers finished at prior barrier

    f32x4 acc[4][2];
#pragma unroll
    for (int fr = 0; fr < 4; ++fr)
#pragma unroll
      for (int fc = 0; fc < 2; ++fc) acc[fr][fc] = (f32x4){0.f, 0.f, 0.f, 0.f};

#pragma unroll
    for (int kc = 0; kc < 8; ++kc) {
      f16x8 bf[2];
#pragma unroll
      for (int fc = 0; fc < 2; ++fc) {
        const int j = (cg * 2 + fc) * 8 + kc;  // this wave's proto-subtile, this kc
        bf[fc] = *reinterpret_cast<const f16x8*>(
            (const char*)ldsB + (buf << 15) + (j << 10) + (size_t)lane * 16);
      }
#pragma unroll
      for (int fr = 0; fr < 4; ++fr)
#pragma unroll
        for (int fc = 0; fc < 2; ++fc)
          acc[fr][fc] = __builtin_amdgcn_mfma_f32_16x16x32_f16(a[fr][kc], bf[fc], acc[fr][fc], 0, 0, 0);
    }

    // ---- fold this chunk's 32 proto-columns (per cg) into quantized top-2 ----
#pragma unroll
    for (int fc = 0; fc < 2; ++fc) {
      const unsigned mp = (unsigned)(1023 - (ch * 64 + cg * 32 + fc * 16 + c));
#pragma unroll
      for (int fr = 0; fr < 4; ++fr)
#pragma unroll
        for (int reg = 0; reg < 4; ++reg) {
          const int s = fr * 4 + reg;
          const float v = acc[fr][fc][reg];
          const unsigned k = ((unsigned)fmaf(v, 32768.0f, 2097152.0f) << 10) | mp;
          const unsigned lo = (k < t1[s]) ? k : t1[s];
          t1[s] = (k > t1[s]) ? k : t1[s];
          t2[s] = (lo > t2[s]) ? lo : t2[s];
        }
    }

    __syncthreads();  // readers of buf done + this iter's DMA (into buf^1) drained
  }

  // ---- cross-lane top-2 merge over the 16 c-lanes sharing each row ----
#pragma unroll
  for (int s = 0; s < 16; ++s) {
#pragma unroll
    for (int off = 1; off <= 8; off <<= 1) {
      const unsigned o1 = (unsigned)__shfl_xor((int)t1[s], off);
      const unsigned o2 = (unsigned)__shfl_xor((int)t2[s], off);
      const unsigned lo = (o1 < t1[s]) ? o1 : t1[s];
      t1[s] = (o1 > t1[s]) ? o1 : t1[s];
      const unsigned hi2 = (o2 > t2[s]) ? o2 : t2[s];
      t2[s] = (lo > hi2) ? lo : hi2;
    }
  }

  // ---- cross-cg merge via LDS (ldsB free after final barrier above) ----
  unsigned* mg = reinterpret_cast<unsigned*>(ldsB);  // [128 rows][2 cg][2]
  if (c == 0) {
#pragma unroll
    for (int s = 0; s < 16; ++s) {
      const int row = rg * 64 + (s >> 2) * 16 + g * 4 + (s & 3);
      mg[(row * 2 + cg) * 2 + 0] = t1[s];
      mg[(row * 2 + cg) * 2 + 1] = t2[s];
    }
  }
  __syncthreads();
  if (tid < 128) {
    const unsigned a1v = mg[(tid * 2 + 0) * 2 + 0], a2v = mg[(tid * 2 + 0) * 2 + 1];
    const unsigned b1v = mg[(tid * 2 + 1) * 2 + 0], b2v = mg[(tid * 2 + 1) * 2 + 1];
    const unsigned lo = (a1v < b1v) ? a1v : b1v;
    const unsigned T1 = (a1v > b1v) ? a1v : b1v;
    unsigned T2 = (a2v > b2v) ? a2v : b2v;
    T2 = (lo > T2) ? lo : T2;
    const int grow = blockRow + tid;
    out[grow] = 1023 - (int)(T1 & 1023u);
    const unsigned iq1 = T1 >> 10, iq2 = T2 >> 10;
    if ((int)(iq1 - iq2) < TAU_Q || iq1 < MASK_Q) {
      const int p = atomicAdd(wcount, 1);
      if (p < wlcap) wl[p] = grow;
    }
  }
}

// ---------------- kernel 3: exact f32 rescue over the worklist (16 rows/batch) ----------------
// Round-1-identical accumulation per (row, proto): ONE ascending-k fmaf chain over k=0..255
// (x,y,z,w within each float4), then v = acc*q, ties to the smaller proto index.
__global__ __launch_bounds__(256) void rescue_kernel(
    const float* __restrict__ E, const float* __restrict__ P,
    const float* __restrict__ q, int* __restrict__ out,
    const int* __restrict__ wcount, const int* __restrict__ wl, int wlcap) {
  __shared__ float Elds[16][260];
  __shared__ int rowsS[16];
  __shared__ float wv[16][4];
  __shared__ int wm[16][4];

  const int tid = threadIdx.x;
  const int wave = tid >> 6, lane = tid & 63;
  int total = *wcount;
  if (total > wlcap) total = wlcap;

  for (int b0 = blockIdx.x * 16; b0 < total; b0 += gridDim.x * 16) {
    const int nb = min(16, total - b0);
    __syncthreads();
    if (tid < 16) rowsS[tid] = wl[b0 + (tid < nb ? tid : 0)];
    __syncthreads();
#pragma unroll
    for (int u = 0; u < 4; ++u) {
      const int unit = u * 256 + tid, r = unit >> 6, k4 = unit & 63;
      *reinterpret_cast<float4*>(&Elds[r][k4 * 4]) =
          *reinterpret_cast<const float4*>(E + (size_t)rowsS[r] * 256 + k4 * 4);
    }
    __syncthreads();

    float acc[16][4];  // 16 rows x 4 protos (m = tid + 256*j)
#pragma unroll
    for (int r = 0; r < 16; ++r)
#pragma unroll
      for (int j = 0; j < 4; ++j) acc[r][j] = 0.f;

    for (int k16 = 0; k16 < 16; ++k16) {  // 16 consecutive k per step
#pragma unroll
      for (int jp = 0; jp < 2; ++jp) {    // protos in pairs (register budget)
        float4 pv[2][4];
#pragma unroll
        for (int jj = 0; jj < 2; ++jj) {
          const float* ps = P + (size_t)(tid + 256 * (jp * 2 + jj)) * 256 + k16 * 16;
#pragma unroll
          for (int u = 0; u < 4; ++u)
            pv[jj][u] = *reinterpret_cast<const float4*>(ps + u * 4);
        }
#pragma unroll
        for (int r = 0; r < 16; ++r) {
#pragma unroll
          for (int jj = 0; jj < 2; ++jj) {
            const int j = jp * 2 + jj;
            float a = acc[r][j];
#pragma unroll
            for (int u = 0; u < 4; ++u) {
              const float4 ev = *reinterpret_cast<const float4*>(&Elds[r][k16 * 16 + u * 4]);
              a = fmaf(pv[jj][u].x, ev.x, a);
              a = fmaf(pv[jj][u].y, ev.y, a);
              a = fmaf(pv[jj][u].z, ev.z, a);
              a = fmaf(pv[jj][u].w, ev.w, a);
            }
            acc[r][j] = a;
          }
        }
      }
    }

    float qv[4];
#pragma unroll
    for (int j = 0; j < 4; ++j) qv[j] = q[tid + 256 * j];

#pragma unroll
    for (int r = 0; r < 16; ++r) {
      float bv = -3.0e38f;
      int bm = 0;
#pragma unroll
      for (int j = 0; j < 4; ++j) {  // m ascending -> strict > keeps lowest m
        const float v = (qv[j] > 0.f) ? acc[r][j] * qv[j] : -1.0e30f;
        if (v > bv) { bv = v; bm = tid + 256 * j; }
      }
#pragma unroll
      for (int off = 1; off <= 32; off <<= 1) {
        const float ov = __shfl_xor(bv, off);
        const int om = __shfl_xor(bm, off);
        if (ov > bv || (ov == bv && om < bm)) { bv = ov; bm = om; }
      }
      if (lane == 0) { wv[r][wave] = bv; wm[r][wave] = bm; }
    }
    __syncthreads();
    if (tid < 16) {
      float bv = wv[tid][0];
      int bm = wm[tid][0];
#pragma unroll
      for (int w = 1; w < 4; ++w) {
        const float ov = wv[tid][w];
        const int om = wm[tid][w];
        if (ov > bv || (ov == bv && om < bm)) { bv = ov; bm = om; }
      }
      if (tid < nb) out[rowsS[tid]] = bm;
    }
    __syncthreads();
  }
}

extern "C" void kernel_launch(void* const* d_in, const int* in_sizes, int n_in,
                              void* d_out, int out_size, void* d_ws, size_t ws_size,
                              hipStream_t stream) {
  const float* E = (const float*)d_in[0];
  const float* P = (const float*)d_in[1];
  const int* counts = (const int*)d_in[2];
  const int M = in_sizes[2];            // 1024
  const int Dd = in_sizes[1] / M;       // 256
  const int N = in_sizes[0] / Dd;       // 65536
  int* out = (int*)d_out;

  // workspace: q (4KB) | wcount @4096 | bhi @8192 (512KB) | worklist @532480
  float* qv = (float*)d_ws;
  int* wcount = (int*)((char*)d_ws + 4096);
  f16x8* bhi = (f16x8*)((char*)d_ws + 8192);
  int* wl = (int*)((char*)d_ws + 8192 + 524288);
  long long cap = ((long long)ws_size - (8192 + 524288)) / 4;
  if (cap < 0) cap = 0;
  if (cap > N) cap = N;
  int wlcap = (int)cap;

  prep_kernel<<<M, 64, 0, stream>>>(P, counts, qv, wcount, bhi);
  screen_kernel<<<N / 128, 256, 0, stream>>>(E, bhi, out, wcount, wl, wlcap);
  rescue_kernel<<<256, 256, 0, stream>>>(E, P, qv, out, wcount, wl, wlcap);
}

// Round 22
// 104.088 us; speedup vs baseline: 1.3381x; 1.0728x over previous
//
#include <hip/hip_runtime.h>
#include <hip/hip_bf16.h>

typedef _Float16 f16x8 __attribute__((ext_vector_type(8)));
typedef float f32x4 __attribute__((ext_vector_type(4)));

#define TAU_Q 164           // ceil(5e-3 * 32768) = 10 sigma of 1-term fp16 dot noise (sigma~5e-4)
#define MASK_Q 2098790u     // (64.05)*32768: best-below -> rescue (masked-proto / all-negative guard)

typedef const __attribute__((address_space(1))) void gas_void;
typedef __attribute__((address_space(3))) void las_void;

__device__ __forceinline__ void gload_lds16(const void* g, void* l) {
  // async global->LDS DMA, 16B/lane; LDS dest = wave-uniform base + lane*16
  __builtin_amdgcn_global_load_lds((gas_void*)g, (las_void*)l, 16, 0, 0);
}

// ---------------- kernel 1: per-proto norm + fp16-hi pack ----------------
// q[m] = counts>0 ? 1/||p_m|| : 0. B-hat = fp16(P*q), packed so MFMA B-fragment
// (p16=m>>4, kc) at lane L sits at byte (p16*8+kc)*1024 + L*16 (coalesced 1KB chunks).
// Chunk property: protos [c*64,(c+1)*64) = bytes [c*32KB,(c+1)*32KB) -- contiguous.
__global__ __launch_bounds__(64) void prep_kernel(
    const float* __restrict__ P, const int* __restrict__ counts,
    float* __restrict__ q, int* __restrict__ wcount, f16x8* __restrict__ bhi) {
  const int m = blockIdx.x, lane = threadIdx.x;
  if (m == 0 && lane == 0) *wcount = 0;
  float4 v = *reinterpret_cast<const float4*>(P + (size_t)m * 256 + lane * 4);
  float s = v.x * v.x + v.y * v.y + v.z * v.z + v.w * v.w;
  for (int off = 32; off > 0; off >>= 1) s += __shfl_xor(s, off, 64);
  const float qm = (counts[m] > 0) ? (1.0f / sqrtf(s)) : 0.0f;
  if (lane == 0) q[m] = qm;
  if (lane < 32) {
    const int kg = lane;  // 8 k-elements per lane
    const float* src = P + (size_t)m * 256 + kg * 8;
    float4 v0 = *reinterpret_cast<const float4*>(src);
    float4 v1 = *reinterpret_cast<const float4*>(src + 4);
    float pe[8] = {v0.x, v0.y, v0.z, v0.w, v1.x, v1.y, v1.z, v1.w};
    f16x8 hi;
#pragma unroll
    for (int t = 0; t < 8; ++t) hi[t] = (_Float16)(pe[t] * qm);
    const int dst = ((m >> 4) * 8 + (kg >> 2)) * 64 + (kg & 3) * 16 + (m & 15);
    bhi[dst] = hi;
  }
}

// ---------------- kernel 2: fp16 MFMA screen -- A-in-reg + coarse dbuf B + 2 resident blocks
// (byte-identical to r21: first variant to break the 70us wall; screen ~45-50us)
__global__ __launch_bounds__(256) void screen_kernel(
    const float* __restrict__ E, const f16x8* __restrict__ bhi,
    int* __restrict__ out, int* __restrict__ wcount,
    int* __restrict__ wl, int wlcap) {
  __shared__ __align__(16) unsigned char ldsB[65536];  // 2 bufs x 32KB (32 chunks of 1KB)

  const int tid = threadIdx.x;
  const int wave = tid >> 6, lane = tid & 63;
  const int rg = wave >> 1, cg = wave & 1;
  const int g = lane >> 4, c = lane & 15;
  const int blockRow = blockIdx.x * 128;
  const char* bhiB = (const char*)bhi;

  // ---- B stage: chunk ch (64 protos, full K) = contiguous 32KB; wave stages 8 fragments ----
  auto stageB = [&](int b, int ch) {
#pragma unroll
    for (int i = 0; i < 8; ++i) {
      const int j = wave * 8 + i;  // fragment 0..31 within chunk
      gload_lds16(bhiB + ((size_t)ch << 15) + ((size_t)j << 10) + (size_t)lane * 16,
                  (char*)ldsB + (b << 15) + (j << 10));
    }
  };

  stageB(0, 0);  // latency hides under the A load+convert below

  // ---- load A into registers: wave's 64 rows x K=256, f32 -> hi fp16, fragment layout ----
  f16x8 a[4][8];
#pragma unroll
  for (int fr = 0; fr < 4; ++fr) {
    const float* rowp = E + (size_t)(blockRow + rg * 64 + fr * 16 + c) * 256 + g * 8;
#pragma unroll
    for (int kc = 0; kc < 8; ++kc) {
      const float* p = rowp + kc * 32;
      float4 v0 = *reinterpret_cast<const float4*>(p);
      float4 v1 = *reinterpret_cast<const float4*>(p + 4);
      f16x8 h;
      h[0] = (_Float16)v0.x; h[1] = (_Float16)v0.y;
      h[2] = (_Float16)v0.z; h[3] = (_Float16)v0.w;
      h[4] = (_Float16)v1.x; h[5] = (_Float16)v1.y;
      h[6] = (_Float16)v1.z; h[7] = (_Float16)v1.w;
      a[fr][kc] = h;
    }
  }
  __syncthreads();  // drains chunk-0 DMA (and syncs the block)

  // quantized top-2 per lane: 16 row-slots (row = rg*64 + (s>>2)*16 + g*4 + (s&3))
  unsigned t1[16], t2[16];
#pragma unroll
  for (int s = 0; s < 16; ++s) { t1[s] = 0u; t2[s] = 0u; }

#pragma unroll 1
  for (int ch = 0; ch < 16; ++ch) {
    const int buf = ch & 1;
    if (ch < 15) stageB(buf ^ 1, ch + 1);  // buf^1's readers finished at prior barrier

    f32x4 acc[4][2];
#pragma unroll
    for (int fr = 0; fr < 4; ++fr)
#pragma unroll
      for (int fc = 0; fc < 2; ++fc) acc[fr][fc] = (f32x4){0.f, 0.f, 0.f, 0.f};

#pragma unroll
    for (int kc = 0; kc < 8; ++kc) {
      f16x8 bf[2];
#pragma unroll
      for (int fc = 0; fc < 2; ++fc) {
        const int j = (cg * 2 + fc) * 8 + kc;  // this wave's proto-subtile, this kc
        bf[fc] = *reinterpret_cast<const f16x8*>(
            (const char*)ldsB + (buf << 15) + (j << 10) + (size_t)lane * 16);
      }
#pragma unroll
      for (int fr = 0; fr < 4; ++fr)
#pragma unroll
        for (int fc = 0; fc < 2; ++fc)
          acc[fr][fc] = __builtin_amdgcn_mfma_f32_16x16x32_f16(a[fr][kc], bf[fc], acc[fr][fc], 0, 0, 0);
    }

    // ---- fold this chunk's 32 proto-columns (per cg) into quantized top-2 ----
#pragma unroll
    for (int fc = 0; fc < 2; ++fc) {
      const unsigned mp = (unsigned)(1023 - (ch * 64 + cg * 32 + fc * 16 + c));
#pragma unroll
      for (int fr = 0; fr < 4; ++fr)
#pragma unroll
        for (int reg = 0; reg < 4; ++reg) {
          const int s = fr * 4 + reg;
          const float v = acc[fr][fc][reg];
          const unsigned k = ((unsigned)fmaf(v, 32768.0f, 2097152.0f) << 10) | mp;
          const unsigned lo = (k < t1[s]) ? k : t1[s];
          t1[s] = (k > t1[s]) ? k : t1[s];
          t2[s] = (lo > t2[s]) ? lo : t2[s];
        }
    }

    __syncthreads();  // readers of buf done + this iter's DMA (into buf^1) drained
  }

  // ---- cross-lane top-2 merge over the 16 c-lanes sharing each row ----
#pragma unroll
  for (int s = 0; s < 16; ++s) {
#pragma unroll
    for (int off = 1; off <= 8; off <<= 1) {
      const unsigned o1 = (unsigned)__shfl_xor((int)t1[s], off);
      const unsigned o2 = (unsigned)__shfl_xor((int)t2[s], off);
      const unsigned lo = (o1 < t1[s]) ? o1 : t1[s];
      t1[s] = (o1 > t1[s]) ? o1 : t1[s];
      const unsigned hi2 = (o2 > t2[s]) ? o2 : t2[s];
      t2[s] = (lo > hi2) ? lo : hi2;
    }
  }

  // ---- cross-cg merge via LDS (ldsB free after final barrier above) ----
  unsigned* mg = reinterpret_cast<unsigned*>(ldsB);  // [128 rows][2 cg][2]
  if (c == 0) {
#pragma unroll
    for (int s = 0; s < 16; ++s) {
      const int row = rg * 64 + (s >> 2) * 16 + g * 4 + (s & 3);
      mg[(row * 2 + cg) * 2 + 0] = t1[s];
      mg[(row * 2 + cg) * 2 + 1] = t2[s];
    }
  }
  __syncthreads();
  if (tid < 128) {
    const unsigned a1v = mg[(tid * 2 + 0) * 2 + 0], a2v = mg[(tid * 2 + 0) * 2 + 1];
    const unsigned b1v = mg[(tid * 2 + 1) * 2 + 0], b2v = mg[(tid * 2 + 1) * 2 + 1];
    const unsigned lo = (a1v < b1v) ? a1v : b1v;
    const unsigned T1 = (a1v > b1v) ? a1v : b1v;
    unsigned T2 = (a2v > b2v) ? a2v : b2v;
    T2 = (lo > T2) ? lo : T2;
    const int grow = blockRow + tid;
    out[grow] = 1023 - (int)(T1 & 1023u);
    const unsigned iq1 = T1 >> 10, iq2 = T2 >> 10;
    if ((int)(iq1 - iq2) < TAU_Q || iq1 < MASK_Q) {
      const int p = atomicAdd(wcount, 1);
      if (p < wlcap) wl[p] = grow;
    }
  }
}

// ---------------- kernel 3: exact f32 rescue -- 4 rows/batch, 512 grid-stride blocks --------
// r21 lesson: 16-row batches on 256 blocks left ~79 blocks active (occupancy 2.8%) with a
// 32K-fmaf serial chain each -> 59us latency-bound tail. 4-row batches on 512 blocks give
// 16x parallelism and a 4x shorter chain. Accumulation stays BIT-IDENTICAL to round-1:
// per (row, proto) one ascending-k fmaf chain (k4 ascending; x,y,z,w within each float4),
// then v = acc*q, strict > with lowest-m tie-break.
__global__ __launch_bounds__(256) void rescue_kernel(
    const float* __restrict__ E, const float* __restrict__ P,
    const float* __restrict__ q, int* __restrict__ out,
    const int* __restrict__ wcount, const int* __restrict__ wl, int wlcap) {
  __shared__ float Elds[4][260];
  __shared__ int rowsS[4];
  __shared__ float wv[4][4];
  __shared__ int wm[4][4];

  const int tid = threadIdx.x;
  const int wave = tid >> 6, lane = tid & 63;
  int total = *wcount;
  if (total > wlcap) total = wlcap;

  for (int b0 = blockIdx.x * 4; b0 < total; b0 += gridDim.x * 4) {
    const int nb = min(4, total - b0);
    __syncthreads();
    if (tid < 4) rowsS[tid] = wl[b0 + (tid < nb ? tid : 0)];
    __syncthreads();
    {  // stage E: 4 rows x 64 float4 = 256 units (one per thread)
      const int r = tid >> 6, k4 = tid & 63;
      *reinterpret_cast<float4*>(&Elds[r][k4 * 4]) =
          *reinterpret_cast<const float4*>(E + (size_t)rowsS[r] * 256 + k4 * 4);
    }
    __syncthreads();

    float acc[4][4];  // [row][proto j]; m = tid + 256*j
#pragma unroll
    for (int r = 0; r < 4; ++r)
#pragma unroll
      for (int j = 0; j < 4; ++j) acc[r][j] = 0.f;

#pragma unroll 4
    for (int k4 = 0; k4 < 64; ++k4) {
      float4 pv[4];
#pragma unroll
      for (int j = 0; j < 4; ++j)
        pv[j] = *reinterpret_cast<const float4*>(P + (size_t)(tid + 256 * j) * 256 + k4 * 4);
      float4 ev[4];
#pragma unroll
      for (int r = 0; r < 4; ++r) ev[r] = *reinterpret_cast<const float4*>(&Elds[r][k4 * 4]);
#pragma unroll
      for (int r = 0; r < 4; ++r)
#pragma unroll
        for (int j = 0; j < 4; ++j) {
          float a = acc[r][j];
          a = fmaf(pv[j].x, ev[r].x, a);
          a = fmaf(pv[j].y, ev[r].y, a);
          a = fmaf(pv[j].z, ev[r].z, a);
          a = fmaf(pv[j].w, ev[r].w, a);
          acc[r][j] = a;
        }
    }

    float qv[4];
#pragma unroll
    for (int j = 0; j < 4; ++j) qv[j] = q[tid + 256 * j];

#pragma unroll
    for (int r = 0; r < 4; ++r) {
      float bv = -3.0e38f;
      int bm = 0;
#pragma unroll
      for (int j = 0; j < 4; ++j) {  // m ascending -> strict > keeps lowest m
        const float v = (qv[j] > 0.f) ? acc[r][j] * qv[j] : -1.0e30f;
        if (v > bv) { bv = v; bm = tid + 256 * j; }
      }
#pragma unroll
      for (int off = 1; off <= 32; off <<= 1) {
        const float ov = __shfl_xor(bv, off);
        const int om = __shfl_xor(bm, off);
        if (ov > bv || (ov == bv && om < bm)) { bv = ov; bm = om; }
      }
      if (lane == 0) { wv[r][wave] = bv; wm[r][wave] = bm; }
    }
    __syncthreads();
    if (tid < 4) {
      float bv = wv[tid][0];
      int bm = wm[tid][0];
#pragma unroll
      for (int w = 1; w < 4; ++w) {
        const float ov = wv[tid][w];
        const int om = wm[tid][w];
        if (ov > bv || (ov == bv && om < bm)) { bv = ov; bm = om; }
      }
      if (tid < nb) out[rowsS[tid]] = bm;
    }
    __syncthreads();
  }
}

extern "C" void kernel_launch(void* const* d_in, const int* in_sizes, int n_in,
                              void* d_out, int out_size, void* d_ws, size_t ws_size,
                              hipStream_t stream) {
  const float* E = (const float*)d_in[0];
  const float* P = (const float*)d_in[1];
  const int* counts = (const int*)d_in[2];
  const int M = in_sizes[2];            // 1024
  const int Dd = in_sizes[1] / M;       // 256
  const int N = in_sizes[0] / Dd;       // 65536
  int* out = (int*)d_out;

  // workspace: q (4KB) | wcount @4096 | bhi @8192 (512KB) | worklist @532480
  float* qv = (float*)d_ws;
  int* wcount = (int*)((char*)d_ws + 4096);
  f16x8* bhi = (f16x8*)((char*)d_ws + 8192);
  int* wl = (int*)((char*)d_ws + 8192 + 524288);
  long long cap = ((long long)ws_size - (8192 + 524288)) / 4;
  if (cap < 0) cap = 0;
  if (cap > N) cap = N;
  int wlcap = (int)cap;

  prep_kernel<<<M, 64, 0, stream>>>(P, counts, qv, wcount, bhi);
  screen_kernel<<<N / 128, 256, 0, stream>>>(E, bhi, out, wcount, wl, wlcap);
  rescue_kernel<<<512, 256, 0, stream>>>(E, P, qv, out, wcount, wl, wlcap);
}